// Round 16
// baseline (180.140 us; speedup 1.0000x reference)
//
#include <hip/hip_runtime.h>
#include <hip/hip_bf16.h>

#define B_ 8
#define C_ 256
#define N_ 4096
#define HID_ 512

typedef __bf16 bf16;
typedef bf16 bf16x8 __attribute__((ext_vector_type(8)));
typedef bf16 bf16x4 __attribute__((ext_vector_type(4)));
typedef float f32x4 __attribute__((ext_vector_type(4)));

// ws layout (bytes) — round-3 footprint (20.9 MB, proven within ws_size). Do not grow.
// wqb/wkb/wvb/m2t are stored FRAGMENT-PACKED: F[p][ks][lane] = M[p*16+(lane&15)][ks*32+(lane>>4)*8+j]
// so every MFMA B-load is 64 lanes x 16B CONTIGUOUS (1 transaction vs 16 scattered).
// QUARANTINED (correctness failures): ws>20.9MB (r4/r5); prefetch-under-stage-2 on the
// 4-wave k_kv (r14 bisect: present in failing r4+r14, absent in all passing rounds).
#define T_OFF    0u           // t bf16 [B*N][256]            16 MB   (t == xn, incl. g_norm)
#define U_OFF    16777216u    // U f32  [B][8][64][64]         1 MB
#define S_OFF    17825792u    // S f32  [B][8][64]            16 KB
#define M2T_OFF  17973248u    // M2T bf16 packed [B][16p][16ks][64][8]  2 MB
#define WQ_OFF   20070400u    // Wq bf16 packed [32p][8ks][64][8]     256 KB
#define WK_OFF   20332544u
#define WV_OFF   20594688u

__device__ __forceinline__ f32x4 mfma16(bf16x8 a, bf16x8 b, f32x4 c) {
    return __builtin_amdgcn_mfma_f32_16x16x32_bf16(a, b, c, 0, 0, 0);
}

__device__ __forceinline__ void gload_lds16(const void* g, void* l) {
    __builtin_amdgcn_global_load_lds(
        (const __attribute__((address_space(1))) unsigned int*)g,
        (__attribute__((address_space(3))) unsigned int*)l, 16, 0, 0);
}

// ---- fused: rmsnorm->t (0..511) + weight cvt PACKED (512..703) + U/S zero (704..735) ----
// Norm branch bounces t through a swizzled LDS tile so the t-store is full 1KB-per-wave
// contiguous lines. (r15-proven)
__global__ void __launch_bounds__(256, 4) k_nc(const float* __restrict__ x,
                                               const float* __restrict__ gnorm,
                                               bf16* __restrict__ t,
                                               const float* __restrict__ wq,
                                               const float* __restrict__ wk,
                                               const float* __restrict__ wv,
                                               bf16* __restrict__ oq,
                                               bf16* __restrict__ ok,
                                               bf16* __restrict__ ov,
                                               float* __restrict__ uz) {
    __shared__ float part[4][64];
    __shared__ __align__(16) bf16 tbuf[64 * 256];   // 32 KB, XOR-swizzled rows of 512B
    if (blockIdx.x >= 704) {
        // zero U (1 MB) + S (16 KB) contiguous = 266240 floats = 66560 f32x4
        const f32x4 z = {0.f, 0.f, 0.f, 0.f};
        int idx = (blockIdx.x - 704) * 256 + threadIdx.x;
        f32x4* dst = (f32x4*)uz;
#pragma unroll
        for (int i = 0; i < 9; ++i) {
            int j = idx + i * 8192;          // 32 blocks * 256 threads
            if (j < 66560) dst[j] = z;
        }
        return;
    }
    if (blockIdx.x >= 512) {
        int bb = blockIdx.x - 512;
        int m = bb >> 6;
        const float* src = (m == 0) ? wq : ((m == 1) ? wk : wv);
        bf16* dst = (m == 0) ? oq : ((m == 1) ? ok : ov);
        int tid = threadIdx.x;
        int i0 = ((bb & 63) * 256 + tid) * 8;   // 8 consecutive k of one row
        f32x4 a = *(const f32x4*)(src + i0);
        f32x4 b2 = *(const f32x4*)(src + i0 + 4);
        bf16x8 o;
#pragma unroll
        for (int j = 0; j < 4; ++j) { o[j] = (bf16)a[j]; o[j + 4] = (bf16)b2[j]; }
        // packed dest: row=(bb&63)*8+(tid>>5), k0=(tid&31)*8
        int row = (bb & 63) * 8 + (tid >> 5);
        int k0 = (tid & 31) * 8;
        int p = row >> 4, l15 = row & 15;
        int ks = k0 >> 5, g = (k0 >> 3) & 3;
        *(bf16x8*)(dst + ((size_t)((p * 8 + ks) * 64 + g * 16 + l15)) * 8) = o;
        return;
    }
    int b = blockIdx.x >> 6;
    int chunk = blockIdx.x & 63;
    int p = threadIdx.x & 63;          // pixel within chunk
    int cq = threadIdx.x >> 6;
    int pix = (chunk << 6) + p;
    const float* xb = x + (size_t)b * C_ * N_ + (size_t)(cq * 64) * N_ + pix;
    float xv[64];
    float ss = 0.f;
#pragma unroll
    for (int c = 0; c < 64; ++c) { xv[c] = xb[(size_t)c * N_]; ss += xv[c] * xv[c]; }
    part[cq][p] = ss;
    __syncthreads();
    float tot = part[0][p] + part[1][p] + part[2][p] + part[3][p];
    float s = 16.0f / fmaxf(sqrtf(tot), 1e-12f);
    // write normalized row-fragment to swizzled LDS (involution: byte ^= (row&7)<<4)
#pragma unroll
    for (int c0 = 0; c0 < 64; c0 += 8) {
        bf16x8 pk;
#pragma unroll
        for (int j = 0; j < 8; ++j)
            pk[j] = (bf16)(xv[c0 + j] * s * gnorm[cq * 64 + c0 + j]);
        int cbyte = cq * 128 + c0 * 2;
        *(bf16x8*)((char*)tbuf + p * 512 + (cbyte ^ ((p & 7) << 4))) = pk;
    }
    __syncthreads();
    // coalesced write-out: plain row-major t; wave writes 1KB contiguous lines
    char* gt = (char*)(t + ((size_t)(b * N_ + (chunk << 6))) * 256);
#pragma unroll
    for (int it = 0; it < 8; ++it) {
        int o = it * 4096 + threadIdx.x * 16;
        int src = o ^ (((o >> 9) & 7) << 4);
        *(f32x4*)(gt + o) = *(const f32x4*)((const char*)tbuf + src);
    }
}

// ---- fused KV projection + U = exp(K)^T V , S = colsum(exp(K)) ----
// EXACT r11/r15-proven form: 4 waves, grid 512 = h(8) x b(8) x chunk(8 of 512 rows),
// one head/block, packed register weights, STAGE at loop top (NO prefetch — quarantined).
__global__ void __launch_bounds__(256, 2) k_kv(const bf16* __restrict__ t,
                                               const bf16* __restrict__ wkb,
                                               const bf16* __restrict__ wvb,
                                               float* __restrict__ U,
                                               float* __restrict__ S) {
    __shared__ __align__(16) bf16 tS[64 * 256];   // 32 KB, rows 512B, XOR-swizzled
    __shared__ __align__(16) bf16 ekT[64][72];    // stride 144B = 9*16 (b128-aligned)
    __shared__ __align__(16) bf16 vT[64][72];
    int h = blockIdx.x >> 6;
    int b = (blockIdx.x >> 3) & 7;
    int chunk = blockIdx.x & 7;
    int w = threadIdx.x >> 6;
    int l = threadIdx.x & 63;
    int l15 = l & 15, g = l >> 4;
    int xorm = (l15 & 7) << 4;

    const bf16* wsel = (w < 2) ? wkb : wvb;
    int c0 = (w & 1) * 32;
    bool isk = (w < 2);
    bf16x8 wf[2][8];
#pragma unroll
    for (int nf = 0; nf < 2; ++nf) {
        int pp = h * 4 + (w & 1) * 2 + nf;   // 16-row panel index
#pragma unroll
        for (int ks = 0; ks < 8; ++ks)
            wf[nf][ks] = *(const bf16x8*)(wsel + ((size_t)((pp * 8 + ks) * 64 + l)) * 8);
    }

    const f32x4 fz = {0.f, 0.f, 0.f, 0.f};
    f32x4 uacc[4];
#pragma unroll
    for (int df = 0; df < 4; ++df) uacc[df] = fz;
    float sreg = 0.f;

    size_t rowbase = (size_t)b * N_ + chunk * 512;
    for (int tile = 0; tile < 8; ++tile) {
        {
            const char* gt = (const char*)(t + (rowbase + tile * 64) * 256);
#pragma unroll
            for (int it = 0; it < 8; ++it) {
                int o = it * 4096 + w * 1024 + l * 16;
                int src = o ^ (((o >> 9) & 7) << 4);
                gload_lds16(gt + src, (char*)tS + it * 4096 + w * 1024);
            }
        }
        __syncthreads();  // vmcnt drained -> tS ready
        f32x4 acc[4][2];
#pragma unroll
        for (int mf = 0; mf < 4; ++mf) { acc[mf][0] = fz; acc[mf][1] = fz; }
#pragma unroll
        for (int ks = 0; ks < 8; ++ks) {
#pragma unroll
            for (int mf = 0; mf < 4; ++mf) {
                bf16x8 a = *(const bf16x8*)((const char*)tS + (mf * 16 + l15) * 512 + ((ks * 64 + g * 16) ^ xorm));
                acc[mf][0] = mfma16(a, wf[0][ks], acc[mf][0]);
                acc[mf][1] = mfma16(a, wf[1][ks], acc[mf][1]);
            }
        }
        __syncthreads();  // stage-1 tS reads + prev stage-2/S ekT/vT reads done
#pragma unroll
        for (int mf = 0; mf < 4; ++mf)
#pragma unroll
            for (int nf = 0; nf < 2; ++nf) {
                int cc = c0 + nf * 16 + l15;
                int rr = mf * 16 + g * 4;
                bf16x4 pk;
#pragma unroll
                for (int r = 0; r < 4; ++r) {
                    float v = acc[mf][nf][r];
                    pk[r] = (bf16)(isk ? __expf(v) : v);
                }
                if (isk) *(bf16x4*)(&ekT[cc][rr]) = pk;
                else     *(bf16x4*)(&vT[cc][rr]) = pk;
            }
        __syncthreads();  // ekT/vT ready
#pragma unroll
        for (int k2 = 0; k2 < 2; ++k2) {
            bf16x8 bv = *(const bf16x8*)(&vT[w * 16 + l15][k2 * 32 + g * 8]);
#pragma unroll
            for (int df = 0; df < 4; ++df) {
                bf16x8 ae = *(const bf16x8*)(&ekT[df * 16 + l15][k2 * 32 + g * 8]);
                uacc[df] = mfma16(ae, bv, uacc[df]);
            }
        }
        {
#pragma unroll
            for (int i = 0; i < 16; ++i) sreg += (float)ekT[l][w * 16 + i];
        }
    }
    int bh = b * 8 + h;
    float* Ubh = U + (size_t)bh * 4096;
#pragma unroll
    for (int df = 0; df < 4; ++df)
#pragma unroll
        for (int r = 0; r < 4; ++r)
            atomicAdd(Ubh + (df * 16 + g * 4 + r) * 64 + w * 16 + l15, uacc[df][r]);
    atomicAdd(S + bh * 64 + l, sreg);
}

// ---- attn = U/S ; M2 packed-fragment output ----
// grid 256; b = idx&7 -> same-XCD as k_qout's batch-b blocks
__global__ void __launch_bounds__(256) k_attn_m2(const float* __restrict__ U,
                                                 const float* __restrict__ S,
                                                 const float* __restrict__ cw,
                                                 bf16* __restrict__ m2t) {
    __shared__ float at[16][64];
    int b = blockIdx.x & 7, dq = (blockIdx.x >> 3) & 3, h = blockIdx.x >> 5;
    int tid = threadIdx.x;
    const float* Ub = U + (size_t)(b * 8 + h) * 4096 + dq * 16 * 64;
    const float* Sb = S + (b * 8 + h) * 64 + dq * 16;
    for (int it = 0; it < 4; ++it) {
        int idx = it * 256 + tid;  // 0..1023
        at[idx >> 6][idx & 63] = Ub[idx] / Sb[idx >> 6];
    }
    __syncthreads();
    int o = tid;
    float cwr[64];
#pragma unroll
    for (int e = 0; e < 64; ++e) cwr[e] = cw[(size_t)o * 512 + h * 64 + e];
    // packed store: M2[o][k], k = h*64 + dq*16 + j0 + j
    bf16* mb = m2t + (size_t)b * 131072;
    int pp = o >> 4, l15o = o & 15;
#pragma unroll
    for (int j0 = 0; j0 < 16; j0 += 8) {
        bf16x8 pk;
#pragma unroll
        for (int j = 0; j < 8; ++j) {
            float a2 = 0.f;
#pragma unroll
            for (int e = 0; e < 64; ++e) a2 += at[j0 + j][e] * cwr[e];
            pk[j] = (bf16)a2;
        }
        int kk = dq * 16 + j0;                 // k within head, 0..56
        int ksg = h * 2 + (kk >> 5);           // global ks (0..15)
        int gg = (kk >> 3) & 3;
        *(bf16x8*)(mb + ((size_t)((pp * 16 + ksg) * 64 + gg * 16 + l15o)) * 8) = pk;
    }
}

// ---- fused: q GEMM + per-head softmax + (qsm @ M2T) + bias + rmsnorm + residual ----
// grid 512 = b(8) x rowtile(64 of 64 rows); 512 threads (8 waves), 2 blocks/CU.
// NEW (r16): ALL B-operand fragments (wqb 32 frags + m2t 32 frags per wave, 256 VGPR)
// hoisted to registers at entry, BEFORE staging issues — the compiler can't hoist loads
// across __syncthreads, so phase-1/3 previously opened with L2-latency-exposed load
// bursts. Now their latency overlaps the 32KB staging drain; phases are pure LDS+reg.
__global__ void __launch_bounds__(512, 4) k_qout(const bf16* __restrict__ t,
                                                 const bf16* __restrict__ wqb,
                                                 const bf16* __restrict__ m2t,
                                                 const float* __restrict__ gffn,
                                                 const float* __restrict__ cb,
                                                 float* __restrict__ out) {
    __shared__ __align__(16) char smem[66560 + 2048];  // qsm/tS/obuf (66560) + rowsum[8][64]
    bf16 (*qsm)[520] = (bf16(*)[520])smem;
    float* rowsum = (float*)(smem + 66560);
    bf16* tS = (bf16*)smem;
    int b = blockIdx.x & 7;
    int row0 = (blockIdx.x >> 3) << 6;
    int tid = threadIdx.x;
    int w = tid >> 6, l = tid & 63;
    int l15 = l & 15, g = l >> 4;
    int xorm = (l15 & 7) << 4;
    const f32x4 fz = {0.f, 0.f, 0.f, 0.f};

    // hoist B fragments (issued first; complete during the staging drain)
    const bf16* mb = m2t + (size_t)b * 131072;
    bf16x8 bqr[4][8], bmr[2][16];
#pragma unroll
    for (int nf = 0; nf < 4; ++nf)
#pragma unroll
        for (int ks = 0; ks < 8; ++ks)
            bqr[nf][ks] = *(const bf16x8*)(wqb + ((size_t)(((w * 4 + nf) * 8 + ks) * 64 + l)) * 8);
#pragma unroll
    for (int nf = 0; nf < 2; ++nf)
#pragma unroll
        for (int ks = 0; ks < 16; ++ks)
            bmr[nf][ks] = *(const bf16x8*)(mb + ((size_t)(((w * 2 + nf) * 16 + ks) * 64 + l)) * 8);

    // stage t[64][256] (32KB) swizzled
    {
        const char* gt = (const char*)(t + (size_t)(b * N_ + row0) * 256);
#pragma unroll
        for (int it = 0; it < 4; ++it) {
            int o = it * 8192 + tid * 16;
            int src = o ^ (((o >> 9) & 7) << 4);
            gload_lds16(gt + src, (char*)tS + o);
        }
    }
    __syncthreads();  // drains vmcnt -> tS ready (B frags also landed)

    // phase 1: q = tS @ WqT (wave w: 64 rows x 64 cols = head w; panels w*4+nf)
    f32x4 acc[4][4];
#pragma unroll
    for (int mf = 0; mf < 4; ++mf)
#pragma unroll
        for (int nf = 0; nf < 4; ++nf) acc[mf][nf] = fz;
#pragma unroll
    for (int ks = 0; ks < 8; ++ks) {
        bf16x8 a[4];
#pragma unroll
        for (int mf = 0; mf < 4; ++mf)
            a[mf] = *(const bf16x8*)((const char*)tS + (mf * 16 + l15) * 512 + ((ks * 64 + g * 16) ^ xorm));
#pragma unroll
        for (int nf = 0; nf < 4; ++nf)
#pragma unroll
            for (int mf = 0; mf < 4; ++mf)
                acc[mf][nf] = mfma16(a[mf], bqr[nf][ks], acc[mf][nf]);
    }
    __syncthreads();  // all tS reads done before qsm overwrite

    // phase 2: softmax over head w's 64 d (this wave's 4 nf panels), -> qsm bf16
#pragma unroll
    for (int mf = 0; mf < 4; ++mf)
#pragma unroll
        for (int r = 0; r < 4; ++r) {
            float mx = -1e30f;
#pragma unroll
            for (int nf = 0; nf < 4; ++nf) mx = fmaxf(mx, acc[mf][nf][r]);
            mx = fmaxf(mx, __shfl_xor(mx, 1));
            mx = fmaxf(mx, __shfl_xor(mx, 2));
            mx = fmaxf(mx, __shfl_xor(mx, 4));
            mx = fmaxf(mx, __shfl_xor(mx, 8));
            float p[4]; float sm = 0.f;
#pragma unroll
            for (int nf = 0; nf < 4; ++nf) { p[nf] = __expf(acc[mf][nf][r] - mx); sm += p[nf]; }
            sm += __shfl_xor(sm, 1);
            sm += __shfl_xor(sm, 2);
            sm += __shfl_xor(sm, 4);
            sm += __shfl_xor(sm, 8);
            float scl = 0.125f / sm;
            int row = mf * 16 + g * 4 + r;
#pragma unroll
            for (int nf = 0; nf < 4; ++nf)
                qsm[row][w * 64 + nf * 16 + l15] = (bf16)(p[nf] * scl);
        }
    __syncthreads();

    // phase 3: out2 = qsm @ M2T (wave w: 64 rows x cols [w*32,w*32+32); panels w*2+nf)
    f32x4 acc2[4][2];
#pragma unroll
    for (int mf = 0; mf < 4; ++mf)
#pragma unroll
        for (int nf = 0; nf < 2; ++nf) acc2[mf][nf] = fz;
#pragma unroll
    for (int ks = 0; ks < 16; ++ks) {
        bf16x8 a[4];
#pragma unroll
        for (int mf = 0; mf < 4; ++mf)
            a[mf] = *(const bf16x8*)(&qsm[mf * 16 + l15][ks * 32 + g * 8]);
#pragma unroll
        for (int nf = 0; nf < 2; ++nf)
#pragma unroll
            for (int mf = 0; mf < 4; ++mf)
                acc2[mf][nf] = mfma16(a[mf], bmr[nf][ks], acc2[mf][nf]);
    }

    // phase 4: +bias, rmsnorm partials over this wave's 32 cols
#pragma unroll
    for (int nf = 0; nf < 2; ++nf) {
        float bias = cb[w * 32 + nf * 16 + l15];
#pragma unroll
        for (int mf = 0; mf < 4; ++mf)
#pragma unroll
            for (int r = 0; r < 4; ++r) acc2[mf][nf][r] += bias;
    }
#pragma unroll
    for (int mf = 0; mf < 4; ++mf)
#pragma unroll
        for (int r = 0; r < 4; ++r) {
            float ssq = 0.f;
#pragma unroll
            for (int nf = 0; nf < 2; ++nf) ssq += acc2[mf][nf][r] * acc2[mf][nf][r];
            ssq += __shfl_xor(ssq, 1);
            ssq += __shfl_xor(ssq, 2);
            ssq += __shfl_xor(ssq, 4);
            ssq += __shfl_xor(ssq, 8);
            if (l15 == 0) rowsum[w * 64 + mf * 16 + g * 4 + r] = ssq;
        }
    __syncthreads();  // rowsum complete + all phase-3 qsm reads done
    float sclr[4][4];
#pragma unroll
    for (int mf = 0; mf < 4; ++mf)
#pragma unroll
        for (int r = 0; r < 4; ++r) {
            int row = mf * 16 + g * 4 + r;
            float tot = 0.f;
#pragma unroll
            for (int ww = 0; ww < 8; ++ww) tot += rowsum[ww * 64 + row];
            sclr[mf][r] = 16.0f / fmaxf(sqrtf(tot), 1e-12f);
        }

    // epilogue: obuf[col][row] = acc2*scl*gffn + residual (re-read t; L2-hot).
    float* obuf = (float*)smem;
    const bf16* gtb = t + (size_t)(b * N_ + row0) * 256;
#pragma unroll
    for (int nf = 0; nf < 2; ++nf) {
        int col = w * 32 + nf * 16 + l15;
        float gf = gffn[col];
#pragma unroll
        for (int mf = 0; mf < 4; ++mf)
#pragma unroll
            for (int r = 0; r < 4; ++r) {
                int row = mf * 16 + g * 4 + r;
                float res = (float)gtb[row * 256 + col];
                obuf[col * 65 + row] = acc2[mf][nf][r] * sclr[mf][r] * gf + res;
            }
    }
    __syncthreads();
    // coalesced read-back: 16 lanes cover one col's 64 floats (256B), nontemporal
#pragma unroll
    for (int cc = 0; cc < 8; ++cc) {
        int c = cc * 32 + (tid >> 4);
        int j = (tid & 15) * 4;
        f32x4 v;
#pragma unroll
        for (int r = 0; r < 4; ++r) v[r] = obuf[c * 65 + j + r];
        __builtin_nontemporal_store(v, (f32x4*)(out + ((size_t)(b * 256 + c)) * N_ + row0 + j));
    }
}

extern "C" void kernel_launch(void* const* d_in, const int* in_sizes, int n_in,
                              void* d_out, int out_size, void* d_ws, size_t ws_size,
                              hipStream_t stream) {
    const float* x     = (const float*)d_in[0];
    const float* Wq    = (const float*)d_in[1];
    const float* Wk    = (const float*)d_in[2];
    const float* Wv    = (const float*)d_in[3];
    const float* cw    = (const float*)d_in[4];
    const float* cb    = (const float*)d_in[5];
    const float* gffn  = (const float*)d_in[6];
    const float* gnorm = (const float*)d_in[7];
    char* ws = (char*)d_ws;
    bf16* t    = (bf16*)(ws + T_OFF);
    float* U   = (float*)(ws + U_OFF);
    float* S   = (float*)(ws + S_OFF);
    bf16* m2t  = (bf16*)(ws + M2T_OFF);
    bf16* wqb  = (bf16*)(ws + WQ_OFF);
    bf16* wkb  = (bf16*)(ws + WK_OFF);
    bf16* wvb  = (bf16*)(ws + WV_OFF);
    float* out = (float*)d_out;

    k_nc<<<736, 256, 0, stream>>>(x, gnorm, t, Wq, Wk, Wv, wqb, wkb, wvb, U);
    k_kv<<<512, 256, 0, stream>>>(t, wkb, wvb, U, S);
    k_attn_m2<<<256, 256, 0, stream>>>(U, S, cw, m2t);
    k_qout<<<512, 512, 0, stream>>>(t, wqb, m2t, gffn, cb, out);
}

// Round 17
// 96.953 us; speedup vs baseline: 1.8580x; 1.8580x over previous
//
#include <hip/hip_runtime.h>
#include <hip/hip_bf16.h>

#define B_ 8
#define C_ 256
#define N_ 4096
#define HID_ 512

typedef __bf16 bf16;
typedef bf16 bf16x8 __attribute__((ext_vector_type(8)));
typedef bf16 bf16x4 __attribute__((ext_vector_type(4)));
typedef float f32x4 __attribute__((ext_vector_type(4)));

// ws layout (bytes) — round-3 footprint (20.9 MB, proven within ws_size). Do not grow.
// wqb/wkb/wvb/m2t are FRAGMENT-PACKED: F[p][ks][lane] = M[p*16+(lane&15)][ks*32+(lane>>4)*8+j]
// QUARANTINED (correctness): ws>20.9MB (r4/r5); prefetch-under-stage-2 on 4-wave k_kv (r14).
// QUARANTINED (perf): 8-wave k_kv (r12/r13); >128-VGPR hoist under launch_bounds(512,4) —
// r16: allocator cap 128 VGPR -> 256-VGPR payload spilled to scratch (WRITE 240MB, 3.5x dur).
#define T_OFF    0u           // t bf16 [B*N][256]            16 MB   (t == xn, incl. g_norm)
#define U_OFF    16777216u    // U f32  [B][8][64][64]         1 MB
#define S_OFF    17825792u    // S f32  [B][8][64]            16 KB
#define M2T_OFF  17973248u    // M2T bf16 packed [B][16p][16ks][64][8]  2 MB
#define WQ_OFF   20070400u    // Wq bf16 packed [32p][8ks][64][8]     256 KB
#define WK_OFF   20332544u
#define WV_OFF   20594688u

__device__ __forceinline__ f32x4 mfma16(bf16x8 a, bf16x8 b, f32x4 c) {
    return __builtin_amdgcn_mfma_f32_16x16x32_bf16(a, b, c, 0, 0, 0);
}

__device__ __forceinline__ void gload_lds16(const void* g, void* l) {
    __builtin_amdgcn_global_load_lds(
        (const __attribute__((address_space(1))) unsigned int*)g,
        (__attribute__((address_space(3))) unsigned int*)l, 16, 0, 0);
}

// ---- fused: rmsnorm->t (0..511) + weight cvt PACKED (512..703) + U/S zero (704..735) ----
// (r15-proven, byte-identical)
__global__ void __launch_bounds__(256, 4) k_nc(const float* __restrict__ x,
                                               const float* __restrict__ gnorm,
                                               bf16* __restrict__ t,
                                               const float* __restrict__ wq,
                                               const float* __restrict__ wk,
                                               const float* __restrict__ wv,
                                               bf16* __restrict__ oq,
                                               bf16* __restrict__ ok,
                                               bf16* __restrict__ ov,
                                               float* __restrict__ uz) {
    __shared__ float part[4][64];
    __shared__ __align__(16) bf16 tbuf[64 * 256];   // 32 KB, XOR-swizzled rows of 512B
    if (blockIdx.x >= 704) {
        const f32x4 z = {0.f, 0.f, 0.f, 0.f};
        int idx = (blockIdx.x - 704) * 256 + threadIdx.x;
        f32x4* dst = (f32x4*)uz;
#pragma unroll
        for (int i = 0; i < 9; ++i) {
            int j = idx + i * 8192;          // 32 blocks * 256 threads
            if (j < 66560) dst[j] = z;
        }
        return;
    }
    if (blockIdx.x >= 512) {
        int bb = blockIdx.x - 512;
        int m = bb >> 6;
        const float* src = (m == 0) ? wq : ((m == 1) ? wk : wv);
        bf16* dst = (m == 0) ? oq : ((m == 1) ? ok : ov);
        int tid = threadIdx.x;
        int i0 = ((bb & 63) * 256 + tid) * 8;   // 8 consecutive k of one row
        f32x4 a = *(const f32x4*)(src + i0);
        f32x4 b2 = *(const f32x4*)(src + i0 + 4);
        bf16x8 o;
#pragma unroll
        for (int j = 0; j < 4; ++j) { o[j] = (bf16)a[j]; o[j + 4] = (bf16)b2[j]; }
        int row = (bb & 63) * 8 + (tid >> 5);
        int k0 = (tid & 31) * 8;
        int p = row >> 4, l15 = row & 15;
        int ks = k0 >> 5, g = (k0 >> 3) & 3;
        *(bf16x8*)(dst + ((size_t)((p * 8 + ks) * 64 + g * 16 + l15)) * 8) = o;
        return;
    }
    int b = blockIdx.x >> 6;
    int chunk = blockIdx.x & 63;
    int p = threadIdx.x & 63;          // pixel within chunk
    int cq = threadIdx.x >> 6;
    int pix = (chunk << 6) + p;
    const float* xb = x + (size_t)b * C_ * N_ + (size_t)(cq * 64) * N_ + pix;
    float xv[64];
    float ss = 0.f;
#pragma unroll
    for (int c = 0; c < 64; ++c) { xv[c] = xb[(size_t)c * N_]; ss += xv[c] * xv[c]; }
    part[cq][p] = ss;
    __syncthreads();
    float tot = part[0][p] + part[1][p] + part[2][p] + part[3][p];
    float s = 16.0f / fmaxf(sqrtf(tot), 1e-12f);
#pragma unroll
    for (int c0 = 0; c0 < 64; c0 += 8) {
        bf16x8 pk;
#pragma unroll
        for (int j = 0; j < 8; ++j)
            pk[j] = (bf16)(xv[c0 + j] * s * gnorm[cq * 64 + c0 + j]);
        int cbyte = cq * 128 + c0 * 2;
        *(bf16x8*)((char*)tbuf + p * 512 + (cbyte ^ ((p & 7) << 4))) = pk;
    }
    __syncthreads();
    char* gt = (char*)(t + ((size_t)(b * N_ + (chunk << 6))) * 256);
#pragma unroll
    for (int it = 0; it < 8; ++it) {
        int o = it * 4096 + threadIdx.x * 16;
        int src = o ^ (((o >> 9) & 7) << 4);
        *(f32x4*)(gt + o) = *(const f32x4*)((const char*)tbuf + src);
    }
}

// ---- fused KV projection + U = exp(K)^T V , S = colsum(exp(K)) ----
// v4: r15's proven 4-wave/256-thread codegen, but TWO heads SEQUENTIALLY per staged
// tile. grid 512 = hp(4) x b(8) x chunk(16 of 256 rows; 4 tiles). Staging traffic
// halves (128->64MB); MFMA per barrier-set doubles. Both heads' weights register-
// resident (wf[2][2][8] ~128 VGPR; launch_bounds(256,2) cap is ample). 2 blocks/CU.
// STAGE stays at loop top (prefetch variant remains quarantined).
__global__ void __launch_bounds__(256, 2) k_kv(const bf16* __restrict__ t,
                                               const bf16* __restrict__ wkb,
                                               const bf16* __restrict__ wvb,
                                               float* __restrict__ U,
                                               float* __restrict__ S) {
    __shared__ __align__(16) bf16 tS[64 * 256];   // 32 KB, rows 512B, XOR-swizzled
    __shared__ __align__(16) bf16 ekT[64][72];    // stride 144B = 9*16 (b128-aligned)
    __shared__ __align__(16) bf16 vT[64][72];
    int hp = blockIdx.x >> 7;          // 0..3 head pair
    int b = (blockIdx.x >> 4) & 7;
    int chunk = blockIdx.x & 15;
    int w = threadIdx.x >> 6;
    int l = threadIdx.x & 63;
    int l15 = l & 15, g = l >> 4;
    int xorm = (l15 & 7) << 4;

    const bf16* wsel = (w < 2) ? wkb : wvb;
    int c0 = (w & 1) * 32;
    bool isk = (w < 2);
    bf16x8 wf[2][2][8];                // [head-in-pair][nf][ks]
#pragma unroll
    for (int hh = 0; hh < 2; ++hh) {
        int h = hp * 2 + hh;
#pragma unroll
        for (int nf = 0; nf < 2; ++nf) {
            int pp = h * 4 + (w & 1) * 2 + nf;   // 16-row panel index
#pragma unroll
            for (int ks = 0; ks < 8; ++ks)
                wf[hh][nf][ks] = *(const bf16x8*)(wsel + ((size_t)((pp * 8 + ks) * 64 + l)) * 8);
        }
    }

    const f32x4 fz = {0.f, 0.f, 0.f, 0.f};
    f32x4 uacc[2][4];
#pragma unroll
    for (int hh = 0; hh < 2; ++hh)
#pragma unroll
        for (int df = 0; df < 4; ++df) uacc[hh][df] = fz;
    float sreg[2] = {0.f, 0.f};

    size_t rowbase = (size_t)b * N_ + chunk * 256;
    for (int tile = 0; tile < 4; ++tile) {
        {
            const char* gt = (const char*)(t + (rowbase + tile * 64) * 256);
#pragma unroll
            for (int it = 0; it < 8; ++it) {
                int o = it * 4096 + w * 1024 + l * 16;
                int src = o ^ (((o >> 9) & 7) << 4);
                gload_lds16(gt + src, (char*)tS + it * 4096 + w * 1024);
            }
        }
        __syncthreads();  // vmcnt drained -> tS ready
#pragma unroll
        for (int hh = 0; hh < 2; ++hh) {
            // stage-1: k/v = tS @ W^T for head hp*2+hh (this wave's 32 cols)
            f32x4 acc[4][2];
#pragma unroll
            for (int mf = 0; mf < 4; ++mf) { acc[mf][0] = fz; acc[mf][1] = fz; }
#pragma unroll
            for (int ks = 0; ks < 8; ++ks) {
#pragma unroll
                for (int mf = 0; mf < 4; ++mf) {
                    bf16x8 a = *(const bf16x8*)((const char*)tS + (mf * 16 + l15) * 512 + ((ks * 64 + g * 16) ^ xorm));
                    acc[mf][0] = mfma16(a, wf[hh][0][ks], acc[mf][0]);
                    acc[mf][1] = mfma16(a, wf[hh][1][ks], acc[mf][1]);
                }
            }
            __syncthreads();  // prior stage-2/S ekT/vT reads done before overwrite
#pragma unroll
            for (int mf = 0; mf < 4; ++mf)
#pragma unroll
                for (int nf = 0; nf < 2; ++nf) {
                    int cc = c0 + nf * 16 + l15;
                    int rr = mf * 16 + g * 4;
                    bf16x4 pk;
#pragma unroll
                    for (int r = 0; r < 4; ++r) {
                        float v = acc[mf][nf][r];
                        pk[r] = (bf16)(isk ? __expf(v) : v);
                    }
                    if (isk) *(bf16x4*)(&ekT[cc][rr]) = pk;
                    else     *(bf16x4*)(&vT[cc][rr]) = pk;
                }
            __syncthreads();  // ekT/vT ready
            // stage-2: U += expK^T V over this tile's 64 rows (e-cols w*16..+16)
#pragma unroll
            for (int k2 = 0; k2 < 2; ++k2) {
                bf16x8 bv = *(const bf16x8*)(&vT[w * 16 + l15][k2 * 32 + g * 8]);
#pragma unroll
                for (int df = 0; df < 4; ++df) {
                    bf16x8 ae = *(const bf16x8*)(&ekT[df * 16 + l15][k2 * 32 + g * 8]);
                    uacc[hh][df] = mfma16(ae, bv, uacc[hh][df]);
                }
            }
            {
                float s8 = 0.f;
#pragma unroll
                for (int i = 0; i < 16; ++i) s8 += (float)ekT[l][w * 16 + i];
                sreg[hh] += s8;
            }
        }
    }
#pragma unroll
    for (int hh = 0; hh < 2; ++hh) {
        int bh = b * 8 + hp * 2 + hh;
        float* Ubh = U + (size_t)bh * 4096;
#pragma unroll
        for (int df = 0; df < 4; ++df)
#pragma unroll
            for (int r = 0; r < 4; ++r)
                atomicAdd(Ubh + (df * 16 + g * 4 + r) * 64 + w * 16 + l15, uacc[hh][df][r]);
        atomicAdd(S + bh * 64 + l, sreg[hh]);
    }
}

// ---- attn = U/S ; M2 packed-fragment output ---- (unchanged)
__global__ void __launch_bounds__(256) k_attn_m2(const float* __restrict__ U,
                                                 const float* __restrict__ S,
                                                 const float* __restrict__ cw,
                                                 bf16* __restrict__ m2t) {
    __shared__ float at[16][64];
    int b = blockIdx.x & 7, dq = (blockIdx.x >> 3) & 3, h = blockIdx.x >> 5;
    int tid = threadIdx.x;
    const float* Ub = U + (size_t)(b * 8 + h) * 4096 + dq * 16 * 64;
    const float* Sb = S + (b * 8 + h) * 64 + dq * 16;
    for (int it = 0; it < 4; ++it) {
        int idx = it * 256 + tid;  // 0..1023
        at[idx >> 6][idx & 63] = Ub[idx] / Sb[idx >> 6];
    }
    __syncthreads();
    int o = tid;
    float cwr[64];
#pragma unroll
    for (int e = 0; e < 64; ++e) cwr[e] = cw[(size_t)o * 512 + h * 64 + e];
    bf16* mb = m2t + (size_t)b * 131072;
    int pp = o >> 4, l15o = o & 15;
#pragma unroll
    for (int j0 = 0; j0 < 16; j0 += 8) {
        bf16x8 pk;
#pragma unroll
        for (int j = 0; j < 8; ++j) {
            float a2 = 0.f;
#pragma unroll
            for (int e = 0; e < 64; ++e) a2 += at[j0 + j][e] * cwr[e];
            pk[j] = (bf16)a2;
        }
        int kk = dq * 16 + j0;                 // k within head, 0..56
        int ksg = h * 2 + (kk >> 5);           // global ks (0..15)
        int gg = (kk >> 3) & 3;
        *(bf16x8*)(mb + ((size_t)((pp * 16 + ksg) * 64 + gg * 16 + l15o)) * 8) = pk;
    }
}

// ---- fused: q GEMM + per-head softmax + (qsm @ M2T) + bias + rmsnorm + residual ----
// EXACT r15-proven form (89.2us round). r16's register-hoist spilled (see quarantine note).
__global__ void __launch_bounds__(512, 4) k_qout(const bf16* __restrict__ t,
                                                 const bf16* __restrict__ wqb,
                                                 const bf16* __restrict__ m2t,
                                                 const float* __restrict__ gffn,
                                                 const float* __restrict__ cb,
                                                 float* __restrict__ out) {
    __shared__ __align__(16) char smem[66560 + 2048];  // qsm/tS/obuf (66560) + rowsum[8][64]
    bf16 (*qsm)[520] = (bf16(*)[520])smem;
    float* rowsum = (float*)(smem + 66560);
    bf16* tS = (bf16*)smem;
    int b = blockIdx.x & 7;
    int row0 = (blockIdx.x >> 3) << 6;
    int tid = threadIdx.x;
    int w = tid >> 6, l = tid & 63;
    int l15 = l & 15, g = l >> 4;
    int xorm = (l15 & 7) << 4;
    const f32x4 fz = {0.f, 0.f, 0.f, 0.f};

    // stage t[64][256] (32KB) swizzled
    {
        const char* gt = (const char*)(t + (size_t)(b * N_ + row0) * 256);
#pragma unroll
        for (int it = 0; it < 4; ++it) {
            int o = it * 8192 + tid * 16;
            int src = o ^ (((o >> 9) & 7) << 4);
            gload_lds16(gt + src, (char*)tS + o);
        }
    }
    __syncthreads();  // drains vmcnt -> tS ready

    // phase 1: q = tS @ WqT (wave w: 64 rows x 64 cols = head w; panels w*4+nf)
    f32x4 acc[4][4];
#pragma unroll
    for (int mf = 0; mf < 4; ++mf)
#pragma unroll
        for (int nf = 0; nf < 4; ++nf) acc[mf][nf] = fz;
#pragma unroll
    for (int ks = 0; ks < 8; ++ks) {
        bf16x8 a[4];
#pragma unroll
        for (int mf = 0; mf < 4; ++mf)
            a[mf] = *(const bf16x8*)((const char*)tS + (mf * 16 + l15) * 512 + ((ks * 64 + g * 16) ^ xorm));
#pragma unroll
        for (int nf = 0; nf < 4; ++nf) {
            bf16x8 bq = *(const bf16x8*)(wqb + ((size_t)(((w * 4 + nf) * 8 + ks) * 64 + l)) * 8);
#pragma unroll
            for (int mf = 0; mf < 4; ++mf)
                acc[mf][nf] = mfma16(a[mf], bq, acc[mf][nf]);
        }
    }
    __syncthreads();  // all tS reads done before qsm overwrite

    // phase 2: softmax over head w's 64 d (this wave's 4 nf panels), -> qsm bf16
#pragma unroll
    for (int mf = 0; mf < 4; ++mf)
#pragma unroll
        for (int r = 0; r < 4; ++r) {
            float mx = -1e30f;
#pragma unroll
            for (int nf = 0; nf < 4; ++nf) mx = fmaxf(mx, acc[mf][nf][r]);
            mx = fmaxf(mx, __shfl_xor(mx, 1));
            mx = fmaxf(mx, __shfl_xor(mx, 2));
            mx = fmaxf(mx, __shfl_xor(mx, 4));
            mx = fmaxf(mx, __shfl_xor(mx, 8));
            float p[4]; float sm = 0.f;
#pragma unroll
            for (int nf = 0; nf < 4; ++nf) { p[nf] = __expf(acc[mf][nf][r] - mx); sm += p[nf]; }
            sm += __shfl_xor(sm, 1);
            sm += __shfl_xor(sm, 2);
            sm += __shfl_xor(sm, 4);
            sm += __shfl_xor(sm, 8);
            float scl = 0.125f / sm;
            int row = mf * 16 + g * 4 + r;
#pragma unroll
            for (int nf = 0; nf < 4; ++nf)
                qsm[row][w * 64 + nf * 16 + l15] = (bf16)(p[nf] * scl);
        }
    __syncthreads();

    // phase 3: out2 = qsm @ M2T (wave w: 64 rows x cols [w*32,w*32+32); panels w*2+nf)
    f32x4 acc2[4][2];
#pragma unroll
    for (int mf = 0; mf < 4; ++mf)
#pragma unroll
        for (int nf = 0; nf < 2; ++nf) acc2[mf][nf] = fz;
    const bf16* mb = m2t + (size_t)b * 131072;
#pragma unroll
    for (int ks = 0; ks < 16; ++ks) {
        bf16x8 a[4];
#pragma unroll
        for (int mf = 0; mf < 4; ++mf)
            a[mf] = *(const bf16x8*)(&qsm[mf * 16 + l15][ks * 32 + g * 8]);
#pragma unroll
        for (int nf = 0; nf < 2; ++nf) {
            bf16x8 bm = *(const bf16x8*)(mb + ((size_t)(((w * 2 + nf) * 16 + ks) * 64 + l)) * 8);
#pragma unroll
            for (int mf = 0; mf < 4; ++mf)
                acc2[mf][nf] = mfma16(a[mf], bm, acc2[mf][nf]);
        }
    }

    // phase 4: +bias, rmsnorm partials over this wave's 32 cols
#pragma unroll
    for (int nf = 0; nf < 2; ++nf) {
        float bias = cb[w * 32 + nf * 16 + l15];
#pragma unroll
        for (int mf = 0; mf < 4; ++mf)
#pragma unroll
            for (int r = 0; r < 4; ++r) acc2[mf][nf][r] += bias;
    }
#pragma unroll
    for (int mf = 0; mf < 4; ++mf)
#pragma unroll
        for (int r = 0; r < 4; ++r) {
            float ssq = 0.f;
#pragma unroll
            for (int nf = 0; nf < 2; ++nf) ssq += acc2[mf][nf][r] * acc2[mf][nf][r];
            ssq += __shfl_xor(ssq, 1);
            ssq += __shfl_xor(ssq, 2);
            ssq += __shfl_xor(ssq, 4);
            ssq += __shfl_xor(ssq, 8);
            if (l15 == 0) rowsum[w * 64 + mf * 16 + g * 4 + r] = ssq;
        }
    __syncthreads();  // rowsum complete + all phase-3 qsm reads done
    float sclr[4][4];
#pragma unroll
    for (int mf = 0; mf < 4; ++mf)
#pragma unroll
        for (int r = 0; r < 4; ++r) {
            int row = mf * 16 + g * 4 + r;
            float tot = 0.f;
#pragma unroll
            for (int ww = 0; ww < 8; ++ww) tot += rowsum[ww * 64 + row];
            sclr[mf][r] = 16.0f / fmaxf(sqrtf(tot), 1e-12f);
        }

    // epilogue: obuf[col][row] = acc2*scl*gffn + residual (re-read t; L2-hot).
    float* obuf = (float*)smem;
    const bf16* gtb = t + (size_t)(b * N_ + row0) * 256;
#pragma unroll
    for (int nf = 0; nf < 2; ++nf) {
        int col = w * 32 + nf * 16 + l15;
        float gf = gffn[col];
#pragma unroll
        for (int mf = 0; mf < 4; ++mf)
#pragma unroll
            for (int r = 0; r < 4; ++r) {
                int row = mf * 16 + g * 4 + r;
                float res = (float)gtb[row * 256 + col];
                obuf[col * 65 + row] = acc2[mf][nf][r] * sclr[mf][r] * gf + res;
            }
    }
    __syncthreads();
    // coalesced read-back: 16 lanes cover one col's 64 floats (256B), nontemporal
#pragma unroll
    for (int cc = 0; cc < 8; ++cc) {
        int c = cc * 32 + (tid >> 4);
        int j = (tid & 15) * 4;
        f32x4 v;
#pragma unroll
        for (int r = 0; r < 4; ++r) v[r] = obuf[c * 65 + j + r];
        __builtin_nontemporal_store(v, (f32x4*)(out + ((size_t)(b * 256 + c)) * N_ + row0 + j));
    }
}

extern "C" void kernel_launch(void* const* d_in, const int* in_sizes, int n_in,
                              void* d_out, int out_size, void* d_ws, size_t ws_size,
                              hipStream_t stream) {
    const float* x     = (const float*)d_in[0];
    const float* Wq    = (const float*)d_in[1];
    const float* Wk    = (const float*)d_in[2];
    const float* Wv    = (const float*)d_in[3];
    const float* cw    = (const float*)d_in[4];
    const float* cb    = (const float*)d_in[5];
    const float* gffn  = (const float*)d_in[6];
    const float* gnorm = (const float*)d_in[7];
    char* ws = (char*)d_ws;
    bf16* t    = (bf16*)(ws + T_OFF);
    float* U   = (float*)(ws + U_OFF);
    float* S   = (float*)(ws + S_OFF);
    bf16* m2t  = (bf16*)(ws + M2T_OFF);
    bf16* wqb  = (bf16*)(ws + WQ_OFF);
    bf16* wkb  = (bf16*)(ws + WK_OFF);
    bf16* wvb  = (bf16*)(ws + WV_OFF);
    float* out = (float*)d_out;

    k_nc<<<736, 256, 0, stream>>>(x, gnorm, t, Wq, Wk, Wv, wqb, wkb, wvb, U);
    k_kv<<<512, 256, 0, stream>>>(t, wkb, wvb, U, S);
    k_attn_m2<<<256, 256, 0, stream>>>(U, S, cw, m2t);
    k_qout<<<512, 512, 0, stream>>>(t, wqb, m2t, gffn, cb, out);
}

// Round 18
// 95.786 us; speedup vs baseline: 1.8806x; 1.0122x over previous
//
#include <hip/hip_runtime.h>
#include <hip/hip_bf16.h>

#define B_ 8
#define C_ 256
#define N_ 4096
#define HID_ 512

typedef __bf16 bf16;
typedef bf16 bf16x8 __attribute__((ext_vector_type(8)));
typedef bf16 bf16x4 __attribute__((ext_vector_type(4)));
typedef float f32x4 __attribute__((ext_vector_type(4)));

// ws layout (bytes) — round-3 footprint (20.9 MB, proven within ws_size). Do not grow.
// wqb/wkb/wvb/m2t are FRAGMENT-PACKED: F[p][ks][lane] = M[p*16+(lane&15)][ks*32+(lane>>4)*8+j]
// QUARANTINED (correctness): ws>20.9MB (r4/r5); prefetch-under-stage-2 on 4-wave k_kv (r14).
// QUARANTINED (perf): ALL k_kv tiling restructures (r12 1-blk/CU, r13 8-wave, r17 2-head
// sequential — each regressed vs the r11/r15 4-wave shape); >128-VGPR hoist under
// launch_bounds(512,4) (r16 scratch spill, WRITE 240MB).
#define T_OFF    0u           // t bf16 [B*N][256]            16 MB   (t == xn, incl. g_norm)
#define U_OFF    16777216u    // U f32  [B][8][64][64]         1 MB
#define S_OFF    17825792u    // S f32  [B][8][64]            16 KB
#define M2T_OFF  17973248u    // M2T bf16 packed [B][16p][16ks][64][8]  2 MB
#define WQ_OFF   20070400u    // Wq bf16 packed [32p][8ks][64][8]     256 KB
#define WK_OFF   20332544u
#define WV_OFF   20594688u

__device__ __forceinline__ f32x4 mfma16(bf16x8 a, bf16x8 b, f32x4 c) {
    return __builtin_amdgcn_mfma_f32_16x16x32_bf16(a, b, c, 0, 0, 0);
}

__device__ __forceinline__ void gload_lds16(const void* g, void* l) {
    __builtin_amdgcn_global_load_lds(
        (const __attribute__((address_space(1))) unsigned int*)g,
        (__attribute__((address_space(3))) unsigned int*)l, 16, 0, 0);
}

// ---- fused: rmsnorm->t (0..511) + weight cvt PACKED (512..703) + U/S zero (704..735) ----
// (r15-proven, byte-identical)
__global__ void __launch_bounds__(256, 4) k_nc(const float* __restrict__ x,
                                               const float* __restrict__ gnorm,
                                               bf16* __restrict__ t,
                                               const float* __restrict__ wq,
                                               const float* __restrict__ wk,
                                               const float* __restrict__ wv,
                                               bf16* __restrict__ oq,
                                               bf16* __restrict__ ok,
                                               bf16* __restrict__ ov,
                                               float* __restrict__ uz) {
    __shared__ float part[4][64];
    __shared__ __align__(16) bf16 tbuf[64 * 256];   // 32 KB, XOR-swizzled rows of 512B
    if (blockIdx.x >= 704) {
        const f32x4 z = {0.f, 0.f, 0.f, 0.f};
        int idx = (blockIdx.x - 704) * 256 + threadIdx.x;
        f32x4* dst = (f32x4*)uz;
#pragma unroll
        for (int i = 0; i < 9; ++i) {
            int j = idx + i * 8192;          // 32 blocks * 256 threads
            if (j < 66560) dst[j] = z;
        }
        return;
    }
    if (blockIdx.x >= 512) {
        int bb = blockIdx.x - 512;
        int m = bb >> 6;
        const float* src = (m == 0) ? wq : ((m == 1) ? wk : wv);
        bf16* dst = (m == 0) ? oq : ((m == 1) ? ok : ov);
        int tid = threadIdx.x;
        int i0 = ((bb & 63) * 256 + tid) * 8;   // 8 consecutive k of one row
        f32x4 a = *(const f32x4*)(src + i0);
        f32x4 b2 = *(const f32x4*)(src + i0 + 4);
        bf16x8 o;
#pragma unroll
        for (int j = 0; j < 4; ++j) { o[j] = (bf16)a[j]; o[j + 4] = (bf16)b2[j]; }
        int row = (bb & 63) * 8 + (tid >> 5);
        int k0 = (tid & 31) * 8;
        int p = row >> 4, l15 = row & 15;
        int ks = k0 >> 5, g = (k0 >> 3) & 3;
        *(bf16x8*)(dst + ((size_t)((p * 8 + ks) * 64 + g * 16 + l15)) * 8) = o;
        return;
    }
    int b = blockIdx.x >> 6;
    int chunk = blockIdx.x & 63;
    int p = threadIdx.x & 63;          // pixel within chunk
    int cq = threadIdx.x >> 6;
    int pix = (chunk << 6) + p;
    const float* xb = x + (size_t)b * C_ * N_ + (size_t)(cq * 64) * N_ + pix;
    float xv[64];
    float ss = 0.f;
#pragma unroll
    for (int c = 0; c < 64; ++c) { xv[c] = xb[(size_t)c * N_]; ss += xv[c] * xv[c]; }
    part[cq][p] = ss;
    __syncthreads();
    float tot = part[0][p] + part[1][p] + part[2][p] + part[3][p];
    float s = 16.0f / fmaxf(sqrtf(tot), 1e-12f);
#pragma unroll
    for (int c0 = 0; c0 < 64; c0 += 8) {
        bf16x8 pk;
#pragma unroll
        for (int j = 0; j < 8; ++j)
            pk[j] = (bf16)(xv[c0 + j] * s * gnorm[cq * 64 + c0 + j]);
        int cbyte = cq * 128 + c0 * 2;
        *(bf16x8*)((char*)tbuf + p * 512 + (cbyte ^ ((p & 7) << 4))) = pk;
    }
    __syncthreads();
    char* gt = (char*)(t + ((size_t)(b * N_ + (chunk << 6))) * 256);
#pragma unroll
    for (int it = 0; it < 8; ++it) {
        int o = it * 4096 + threadIdx.x * 16;
        int src = o ^ (((o >> 9) & 7) << 4);
        *(f32x4*)(gt + o) = *(const f32x4*)((const char*)tbuf + src);
    }
}

// ---- fused KV projection + U = exp(K)^T V , S = colsum(exp(K)) ----
// r11/r15-proven 4-wave shape (grid 512 = h(8) x b(8) x chunk(8 of 512 rows), one
// head/block, packed register weights, STAGE at loop top). ONE change vs r15:
// S computed via MFMA-with-ones (S = expK^T · 1, reusing the already-loaded ae
// fragments) instead of the scalar ekT[l][..] loop — that loop was an 8-way
// bank-conflicted 16-read serial chain (SQ_LDS_BANK_CONFLICT 3.3M).
__global__ void __launch_bounds__(256, 2) k_kv(const bf16* __restrict__ t,
                                               const bf16* __restrict__ wkb,
                                               const bf16* __restrict__ wvb,
                                               float* __restrict__ U,
                                               float* __restrict__ S) {
    __shared__ __align__(16) bf16 tS[64 * 256];   // 32 KB, rows 512B, XOR-swizzled
    __shared__ __align__(16) bf16 ekT[64][72];    // stride 144B = 9*16 (b128-aligned)
    __shared__ __align__(16) bf16 vT[64][72];
    int h = blockIdx.x >> 6;
    int b = (blockIdx.x >> 3) & 7;
    int chunk = blockIdx.x & 7;
    int w = threadIdx.x >> 6;
    int l = threadIdx.x & 63;
    int l15 = l & 15, g = l >> 4;
    int xorm = (l15 & 7) << 4;

    const bf16* wsel = (w < 2) ? wkb : wvb;
    int c0 = (w & 1) * 32;
    bool isk = (w < 2);
    bf16x8 wf[2][8];
#pragma unroll
    for (int nf = 0; nf < 2; ++nf) {
        int pp = h * 4 + (w & 1) * 2 + nf;   // 16-row panel index
#pragma unroll
        for (int ks = 0; ks < 8; ++ks)
            wf[nf][ks] = *(const bf16x8*)(wsel + ((size_t)((pp * 8 + ks) * 64 + l)) * 8);
    }

    bf16x8 ones;
#pragma unroll
    for (int j = 0; j < 8; ++j) ones[j] = (bf16)1.0f;

    const f32x4 fz = {0.f, 0.f, 0.f, 0.f};
    f32x4 uacc[4], sacc[4];
#pragma unroll
    for (int df = 0; df < 4; ++df) { uacc[df] = fz; sacc[df] = fz; }

    size_t rowbase = (size_t)b * N_ + chunk * 512;
    for (int tile = 0; tile < 8; ++tile) {
        {
            const char* gt = (const char*)(t + (rowbase + tile * 64) * 256);
#pragma unroll
            for (int it = 0; it < 8; ++it) {
                int o = it * 4096 + w * 1024 + l * 16;
                int src = o ^ (((o >> 9) & 7) << 4);
                gload_lds16(gt + src, (char*)tS + it * 4096 + w * 1024);
            }
        }
        __syncthreads();  // vmcnt drained -> tS ready
        f32x4 acc[4][2];
#pragma unroll
        for (int mf = 0; mf < 4; ++mf) { acc[mf][0] = fz; acc[mf][1] = fz; }
#pragma unroll
        for (int ks = 0; ks < 8; ++ks) {
#pragma unroll
            for (int mf = 0; mf < 4; ++mf) {
                bf16x8 a = *(const bf16x8*)((const char*)tS + (mf * 16 + l15) * 512 + ((ks * 64 + g * 16) ^ xorm));
                acc[mf][0] = mfma16(a, wf[0][ks], acc[mf][0]);
                acc[mf][1] = mfma16(a, wf[1][ks], acc[mf][1]);
            }
        }
        __syncthreads();  // stage-1 tS reads + prev stage-2 ekT/vT reads done
#pragma unroll
        for (int mf = 0; mf < 4; ++mf)
#pragma unroll
            for (int nf = 0; nf < 2; ++nf) {
                int cc = c0 + nf * 16 + l15;
                int rr = mf * 16 + g * 4;
                bf16x4 pk;
#pragma unroll
                for (int r = 0; r < 4; ++r) {
                    float v = acc[mf][nf][r];
                    pk[r] = (bf16)(isk ? __expf(v) : v);
                }
                if (isk) *(bf16x4*)(&ekT[cc][rr]) = pk;
                else     *(bf16x4*)(&vT[cc][rr]) = pk;
            }
        __syncthreads();  // ekT/vT ready
#pragma unroll
        for (int k2 = 0; k2 < 2; ++k2) {
            bf16x8 bv = *(const bf16x8*)(&vT[w * 16 + l15][k2 * 32 + g * 8]);
#pragma unroll
            for (int df = 0; df < 4; ++df) {
                bf16x8 ae = *(const bf16x8*)(&ekT[df * 16 + l15][k2 * 32 + g * 8]);
                uacc[df] = mfma16(ae, bv, uacc[df]);
                sacc[df] = mfma16(ae, ones, sacc[df]);  // S-partial: every col = rowsum
            }
        }
    }
    int bh = b * 8 + h;
    float* Ubh = U + (size_t)bh * 4096;
#pragma unroll
    for (int df = 0; df < 4; ++df)
#pragma unroll
        for (int r = 0; r < 4; ++r) {
            atomicAdd(Ubh + (df * 16 + g * 4 + r) * 64 + w * 16 + l15, uacc[df][r]);
            if (l15 == 0)
                atomicAdd(S + bh * 64 + df * 16 + g * 4 + r, sacc[df][r]);
        }
}

// ---- attn = U/S ; M2 packed-fragment output ---- (r15-proven, unchanged)
__global__ void __launch_bounds__(256) k_attn_m2(const float* __restrict__ U,
                                                 const float* __restrict__ S,
                                                 const float* __restrict__ cw,
                                                 bf16* __restrict__ m2t) {
    __shared__ float at[16][64];
    int b = blockIdx.x & 7, dq = (blockIdx.x >> 3) & 3, h = blockIdx.x >> 5;
    int tid = threadIdx.x;
    const float* Ub = U + (size_t)(b * 8 + h) * 4096 + dq * 16 * 64;
    const float* Sb = S + (b * 8 + h) * 64 + dq * 16;
    for (int it = 0; it < 4; ++it) {
        int idx = it * 256 + tid;  // 0..1023
        at[idx >> 6][idx & 63] = Ub[idx] / Sb[idx >> 6];
    }
    __syncthreads();
    int o = tid;
    float cwr[64];
#pragma unroll
    for (int e = 0; e < 64; ++e) cwr[e] = cw[(size_t)o * 512 + h * 64 + e];
    bf16* mb = m2t + (size_t)b * 131072;
    int pp = o >> 4, l15o = o & 15;
#pragma unroll
    for (int j0 = 0; j0 < 16; j0 += 8) {
        bf16x8 pk;
#pragma unroll
        for (int j = 0; j < 8; ++j) {
            float a2 = 0.f;
#pragma unroll
            for (int e = 0; e < 64; ++e) a2 += at[j0 + j][e] * cwr[e];
            pk[j] = (bf16)a2;
        }
        int kk = dq * 16 + j0;                 // k within head, 0..56
        int ksg = h * 2 + (kk >> 5);           // global ks (0..15)
        int gg = (kk >> 3) & 3;
        *(bf16x8*)(mb + ((size_t)((pp * 16 + ksg) * 64 + gg * 16 + l15o)) * 8) = pk;
    }
}

// ---- fused: q GEMM + per-head softmax + (qsm @ M2T) + bias + rmsnorm + residual ----
// EXACT r15-proven form (89.2us round).
__global__ void __launch_bounds__(512, 4) k_qout(const bf16* __restrict__ t,
                                                 const bf16* __restrict__ wqb,
                                                 const bf16* __restrict__ m2t,
                                                 const float* __restrict__ gffn,
                                                 const float* __restrict__ cb,
                                                 float* __restrict__ out) {
    __shared__ __align__(16) char smem[66560 + 2048];  // qsm/tS/obuf (66560) + rowsum[8][64]
    bf16 (*qsm)[520] = (bf16(*)[520])smem;
    float* rowsum = (float*)(smem + 66560);
    bf16* tS = (bf16*)smem;
    int b = blockIdx.x & 7;
    int row0 = (blockIdx.x >> 3) << 6;
    int tid = threadIdx.x;
    int w = tid >> 6, l = tid & 63;
    int l15 = l & 15, g = l >> 4;
    int xorm = (l15 & 7) << 4;
    const f32x4 fz = {0.f, 0.f, 0.f, 0.f};

    // stage t[64][256] (32KB) swizzled
    {
        const char* gt = (const char*)(t + (size_t)(b * N_ + row0) * 256);
#pragma unroll
        for (int it = 0; it < 4; ++it) {
            int o = it * 8192 + tid * 16;
            int src = o ^ (((o >> 9) & 7) << 4);
            gload_lds16(gt + src, (char*)tS + o);
        }
    }
    __syncthreads();  // drains vmcnt -> tS ready

    // phase 1: q = tS @ WqT (wave w: 64 rows x 64 cols = head w; panels w*4+nf)
    f32x4 acc[4][4];
#pragma unroll
    for (int mf = 0; mf < 4; ++mf)
#pragma unroll
        for (int nf = 0; nf < 4; ++nf) acc[mf][nf] = fz;
#pragma unroll
    for (int ks = 0; ks < 8; ++ks) {
        bf16x8 a[4];
#pragma unroll
        for (int mf = 0; mf < 4; ++mf)
            a[mf] = *(const bf16x8*)((const char*)tS + (mf * 16 + l15) * 512 + ((ks * 64 + g * 16) ^ xorm));
#pragma unroll
        for (int nf = 0; nf < 4; ++nf) {
            bf16x8 bq = *(const bf16x8*)(wqb + ((size_t)(((w * 4 + nf) * 8 + ks) * 64 + l)) * 8);
#pragma unroll
            for (int mf = 0; mf < 4; ++mf)
                acc[mf][nf] = mfma16(a[mf], bq, acc[mf][nf]);
        }
    }
    __syncthreads();  // all tS reads done before qsm overwrite

    // phase 2: softmax over head w's 64 d (this wave's 4 nf panels), -> qsm bf16
#pragma unroll
    for (int mf = 0; mf < 4; ++mf)
#pragma unroll
        for (int r = 0; r < 4; ++r) {
            float mx = -1e30f;
#pragma unroll
            for (int nf = 0; nf < 4; ++nf) mx = fmaxf(mx, acc[mf][nf][r]);
            mx = fmaxf(mx, __shfl_xor(mx, 1));
            mx = fmaxf(mx, __shfl_xor(mx, 2));
            mx = fmaxf(mx, __shfl_xor(mx, 4));
            mx = fmaxf(mx, __shfl_xor(mx, 8));
            float p[4]; float sm = 0.f;
#pragma unroll
            for (int nf = 0; nf < 4; ++nf) { p[nf] = __expf(acc[mf][nf][r] - mx); sm += p[nf]; }
            sm += __shfl_xor(sm, 1);
            sm += __shfl_xor(sm, 2);
            sm += __shfl_xor(sm, 4);
            sm += __shfl_xor(sm, 8);
            float scl = 0.125f / sm;
            int row = mf * 16 + g * 4 + r;
#pragma unroll
            for (int nf = 0; nf < 4; ++nf)
                qsm[row][w * 64 + nf * 16 + l15] = (bf16)(p[nf] * scl);
        }
    __syncthreads();

    // phase 3: out2 = qsm @ M2T (wave w: 64 rows x cols [w*32,w*32+32); panels w*2+nf)
    f32x4 acc2[4][2];
#pragma unroll
    for (int mf = 0; mf < 4; ++mf)
#pragma unroll
        for (int nf = 0; nf < 2; ++nf) acc2[mf][nf] = fz;
    const bf16* mb = m2t + (size_t)b * 131072;
#pragma unroll
    for (int ks = 0; ks < 16; ++ks) {
        bf16x8 a[4];
#pragma unroll
        for (int mf = 0; mf < 4; ++mf)
            a[mf] = *(const bf16x8*)(&qsm[mf * 16 + l15][ks * 32 + g * 8]);
#pragma unroll
        for (int nf = 0; nf < 2; ++nf) {
            bf16x8 bm = *(const bf16x8*)(mb + ((size_t)(((w * 2 + nf) * 16 + ks) * 64 + l)) * 8);
#pragma unroll
            for (int mf = 0; mf < 4; ++mf)
                acc2[mf][nf] = mfma16(a[mf], bm, acc2[mf][nf]);
        }
    }

    // phase 4: +bias, rmsnorm partials over this wave's 32 cols
#pragma unroll
    for (int nf = 0; nf < 2; ++nf) {
        float bias = cb[w * 32 + nf * 16 + l15];
#pragma unroll
        for (int mf = 0; mf < 4; ++mf)
#pragma unroll
            for (int r = 0; r < 4; ++r) acc2[mf][nf][r] += bias;
    }
#pragma unroll
    for (int mf = 0; mf < 4; ++mf)
#pragma unroll
        for (int r = 0; r < 4; ++r) {
            float ssq = 0.f;
#pragma unroll
            for (int nf = 0; nf < 2; ++nf) ssq += acc2[mf][nf][r] * acc2[mf][nf][r];
            ssq += __shfl_xor(ssq, 1);
            ssq += __shfl_xor(ssq, 2);
            ssq += __shfl_xor(ssq, 4);
            ssq += __shfl_xor(ssq, 8);
            if (l15 == 0) rowsum[w * 64 + mf * 16 + g * 4 + r] = ssq;
        }
    __syncthreads();  // rowsum complete + all phase-3 qsm reads done
    float sclr[4][4];
#pragma unroll
    for (int mf = 0; mf < 4; ++mf)
#pragma unroll
        for (int r = 0; r < 4; ++r) {
            int row = mf * 16 + g * 4 + r;
            float tot = 0.f;
#pragma unroll
            for (int ww = 0; ww < 8; ++ww) tot += rowsum[ww * 64 + row];
            sclr[mf][r] = 16.0f / fmaxf(sqrtf(tot), 1e-12f);
        }

    // epilogue: obuf[col][row] = acc2*scl*gffn + residual (re-read t; L2-hot).
    float* obuf = (float*)smem;
    const bf16* gtb = t + (size_t)(b * N_ + row0) * 256;
#pragma unroll
    for (int nf = 0; nf < 2; ++nf) {
        int col = w * 32 + nf * 16 + l15;
        float gf = gffn[col];
#pragma unroll
        for (int mf = 0; mf < 4; ++mf)
#pragma unroll
            for (int r = 0; r < 4; ++r) {
                int row = mf * 16 + g * 4 + r;
                float res = (float)gtb[row * 256 + col];
                obuf[col * 65 + row] = acc2[mf][nf][r] * sclr[mf][r] * gf + res;
            }
    }
    __syncthreads();
    // coalesced read-back: 16 lanes cover one col's 64 floats (256B), nontemporal
#pragma unroll
    for (int cc = 0; cc < 8; ++cc) {
        int c = cc * 32 + (tid >> 4);
        int j = (tid & 15) * 4;
        f32x4 v;
#pragma unroll
        for (int r = 0; r < 4; ++r) v[r] = obuf[c * 65 + j + r];
        __builtin_nontemporal_store(v, (f32x4*)(out + ((size_t)(b * 256 + c)) * N_ + row0 + j));
    }
}

extern "C" void kernel_launch(void* const* d_in, const int* in_sizes, int n_in,
                              void* d_out, int out_size, void* d_ws, size_t ws_size,
                              hipStream_t stream) {
    const float* x     = (const float*)d_in[0];
    const float* Wq    = (const float*)d_in[1];
    const float* Wk    = (const float*)d_in[2];
    const float* Wv    = (const float*)d_in[3];
    const float* cw    = (const float*)d_in[4];
    const float* cb    = (const float*)d_in[5];
    const float* gffn  = (const float*)d_in[6];
    const float* gnorm = (const float*)d_in[7];
    char* ws = (char*)d_ws;
    bf16* t    = (bf16*)(ws + T_OFF);
    float* U   = (float*)(ws + U_OFF);
    float* S   = (float*)(ws + S_OFF);
    bf16* m2t  = (bf16*)(ws + M2T_OFF);
    bf16* wqb  = (bf16*)(ws + WQ_OFF);
    bf16* wkb  = (bf16*)(ws + WK_OFF);
    bf16* wvb  = (bf16*)(ws + WV_OFF);
    float* out = (float*)d_out;

    k_nc<<<736, 256, 0, stream>>>(x, gnorm, t, Wq, Wk, Wv, wqb, wkb, wvb, U);
    k_kv<<<512, 256, 0, stream>>>(t, wkb, wvb, U, S);
    k_attn_m2<<<256, 256, 0, stream>>>(U, S, cw, m2t);
    k_qout<<<512, 512, 0, stream>>>(t, wqb, m2t, gffn, cb, out);
}

// Round 19
// 87.071 us; speedup vs baseline: 2.0689x; 1.1001x over previous
//
#include <hip/hip_runtime.h>
#include <hip/hip_bf16.h>

#define B_ 8
#define C_ 256
#define N_ 4096
#define HID_ 512

typedef __bf16 bf16;
typedef bf16 bf16x8 __attribute__((ext_vector_type(8)));
typedef bf16 bf16x4 __attribute__((ext_vector_type(4)));
typedef float f32x4 __attribute__((ext_vector_type(4)));

// ws layout (bytes) — round-3 footprint (20.9 MB, proven within ws_size). Do not grow.
// wqb/wkb/wvb/m2t are FRAGMENT-PACKED: F[p][ks][lane] = M[p*16+(lane&15)][ks*32+(lane>>4)*8+j]
// QUARANTINED (correctness): ws>20.9MB (r4/r5); prefetch-under-stage-2 on 4-wave k_kv (r14).
// QUARANTINED (perf): k_kv tiling restructures (r12/r13/r17); >128-VGPR hoist under
// launch_bounds(512,4) (r16 scratch spill); MFMA-ones S-path (r18: +7us vs scalar).
#define T_OFF    0u           // t bf16 [B*N][256]            16 MB   (t == xn, incl. g_norm)
#define U_OFF    16777216u    // U f32  [B][8][64][64]         1 MB
#define S_OFF    17825792u    // S f32  [B][8][64]            16 KB
#define M2T_OFF  17973248u    // M2T bf16 packed [B][16p][16ks][64][8]  2 MB
#define WQ_OFF   20070400u    // Wq bf16 packed [32p][8ks][64][8]     256 KB
#define WK_OFF   20332544u
#define WV_OFF   20594688u

__device__ __forceinline__ f32x4 mfma16(bf16x8 a, bf16x8 b, f32x4 c) {
    return __builtin_amdgcn_mfma_f32_16x16x32_bf16(a, b, c, 0, 0, 0);
}

__device__ __forceinline__ void gload_lds16(const void* g, void* l) {
    __builtin_amdgcn_global_load_lds(
        (const __attribute__((address_space(1))) unsigned int*)g,
        (__attribute__((address_space(3))) unsigned int*)l, 16, 0, 0);
}

// ---- fused: rmsnorm->t (0..511) + weight cvt PACKED (512..703) + U/S zero (704..735) ----
// (r15-proven, byte-identical)
__global__ void __launch_bounds__(256, 4) k_nc(const float* __restrict__ x,
                                               const float* __restrict__ gnorm,
                                               bf16* __restrict__ t,
                                               const float* __restrict__ wq,
                                               const float* __restrict__ wk,
                                               const float* __restrict__ wv,
                                               bf16* __restrict__ oq,
                                               bf16* __restrict__ ok,
                                               bf16* __restrict__ ov,
                                               float* __restrict__ uz) {
    __shared__ float part[4][64];
    __shared__ __align__(16) bf16 tbuf[64 * 256];   // 32 KB, XOR-swizzled rows of 512B
    if (blockIdx.x >= 704) {
        const f32x4 z = {0.f, 0.f, 0.f, 0.f};
        int idx = (blockIdx.x - 704) * 256 + threadIdx.x;
        f32x4* dst = (f32x4*)uz;
#pragma unroll
        for (int i = 0; i < 9; ++i) {
            int j = idx + i * 8192;          // 32 blocks * 256 threads
            if (j < 66560) dst[j] = z;
        }
        return;
    }
    if (blockIdx.x >= 512) {
        int bb = blockIdx.x - 512;
        int m = bb >> 6;
        const float* src = (m == 0) ? wq : ((m == 1) ? wk : wv);
        bf16* dst = (m == 0) ? oq : ((m == 1) ? ok : ov);
        int tid = threadIdx.x;
        int i0 = ((bb & 63) * 256 + tid) * 8;   // 8 consecutive k of one row
        f32x4 a = *(const f32x4*)(src + i0);
        f32x4 b2 = *(const f32x4*)(src + i0 + 4);
        bf16x8 o;
#pragma unroll
        for (int j = 0; j < 4; ++j) { o[j] = (bf16)a[j]; o[j + 4] = (bf16)b2[j]; }
        int row = (bb & 63) * 8 + (tid >> 5);
        int k0 = (tid & 31) * 8;
        int p = row >> 4, l15 = row & 15;
        int ks = k0 >> 5, g = (k0 >> 3) & 3;
        *(bf16x8*)(dst + ((size_t)((p * 8 + ks) * 64 + g * 16 + l15)) * 8) = o;
        return;
    }
    int b = blockIdx.x >> 6;
    int chunk = blockIdx.x & 63;
    int p = threadIdx.x & 63;          // pixel within chunk
    int cq = threadIdx.x >> 6;
    int pix = (chunk << 6) + p;
    const float* xb = x + (size_t)b * C_ * N_ + (size_t)(cq * 64) * N_ + pix;
    float xv[64];
    float ss = 0.f;
#pragma unroll
    for (int c = 0; c < 64; ++c) { xv[c] = xb[(size_t)c * N_]; ss += xv[c] * xv[c]; }
    part[cq][p] = ss;
    __syncthreads();
    float tot = part[0][p] + part[1][p] + part[2][p] + part[3][p];
    float s = 16.0f / fmaxf(sqrtf(tot), 1e-12f);
#pragma unroll
    for (int c0 = 0; c0 < 64; c0 += 8) {
        bf16x8 pk;
#pragma unroll
        for (int j = 0; j < 8; ++j)
            pk[j] = (bf16)(xv[c0 + j] * s * gnorm[cq * 64 + c0 + j]);
        int cbyte = cq * 128 + c0 * 2;
        *(bf16x8*)((char*)tbuf + p * 512 + (cbyte ^ ((p & 7) << 4))) = pk;
    }
    __syncthreads();
    char* gt = (char*)(t + ((size_t)(b * N_ + (chunk << 6))) * 256);
#pragma unroll
    for (int it = 0; it < 8; ++it) {
        int o = it * 4096 + threadIdx.x * 16;
        int src = o ^ (((o >> 9) & 7) << 4);
        *(f32x4*)(gt + o) = *(const f32x4*)((const char*)tbuf + src);
    }
}

// ---- fused KV projection + U = exp(K)^T V , S = colsum(exp(K)) ----
// r15 shape with ONE change: ekT/vT are DOUBLE-BUFFERED, removing the middle barrier
// (which only protected ekT/vT against the previous tile's stage-2 reads). 2 barriers/
// tile instead of 3 (24->16 per block). LDS 51.2->69.6KB, still 2 blocks/CU.
// STAGE stays at loop top (prefetch quarantined); S-path = r15 scalar loop (MFMA-ones
// variant quarantined: r18 regression).
__global__ void __launch_bounds__(256, 2) k_kv(const bf16* __restrict__ t,
                                               const bf16* __restrict__ wkb,
                                               const bf16* __restrict__ wvb,
                                               float* __restrict__ U,
                                               float* __restrict__ S) {
    __shared__ __align__(16) bf16 tS[64 * 256];      // 32 KB, rows 512B, XOR-swizzled
    __shared__ __align__(16) bf16 ekT[2][64][72];    // dbuf; stride 144B = 9*16
    __shared__ __align__(16) bf16 vT[2][64][72];
    int h = blockIdx.x >> 6;
    int b = (blockIdx.x >> 3) & 7;
    int chunk = blockIdx.x & 7;
    int w = threadIdx.x >> 6;
    int l = threadIdx.x & 63;
    int l15 = l & 15, g = l >> 4;
    int xorm = (l15 & 7) << 4;

    const bf16* wsel = (w < 2) ? wkb : wvb;
    int c0 = (w & 1) * 32;
    bool isk = (w < 2);
    bf16x8 wf[2][8];
#pragma unroll
    for (int nf = 0; nf < 2; ++nf) {
        int pp = h * 4 + (w & 1) * 2 + nf;   // 16-row panel index
#pragma unroll
        for (int ks = 0; ks < 8; ++ks)
            wf[nf][ks] = *(const bf16x8*)(wsel + ((size_t)((pp * 8 + ks) * 64 + l)) * 8);
    }

    const f32x4 fz = {0.f, 0.f, 0.f, 0.f};
    f32x4 uacc[4];
#pragma unroll
    for (int df = 0; df < 4; ++df) uacc[df] = fz;
    float sreg = 0.f;

    size_t rowbase = (size_t)b * N_ + chunk * 512;
    for (int tile = 0; tile < 8; ++tile) {
        int bs = tile & 1;
        {
            const char* gt = (const char*)(t + (rowbase + tile * 64) * 256);
#pragma unroll
            for (int it = 0; it < 8; ++it) {
                int o = it * 4096 + w * 1024 + l * 16;
                int src = o ^ (((o >> 9) & 7) << 4);
                gload_lds16(gt + src, (char*)tS + it * 4096 + w * 1024);
            }
        }
        __syncthreads();  // vmcnt drained -> tS ready; all waves past stage-2(tile-1)
        f32x4 acc[4][2];
#pragma unroll
        for (int mf = 0; mf < 4; ++mf) { acc[mf][0] = fz; acc[mf][1] = fz; }
#pragma unroll
        for (int ks = 0; ks < 8; ++ks) {
#pragma unroll
            for (int mf = 0; mf < 4; ++mf) {
                bf16x8 a = *(const bf16x8*)((const char*)tS + (mf * 16 + l15) * 512 + ((ks * 64 + g * 16) ^ xorm));
                acc[mf][0] = mfma16(a, wf[0][ks], acc[mf][0]);
                acc[mf][1] = mfma16(a, wf[1][ks], acc[mf][1]);
            }
        }
        // write exp(k)/v into buffer bs — prior reads of this buffer were tile-2 (done);
        // no wave is in stage-2 here (all between barrier-A and barrier-B).
#pragma unroll
        for (int mf = 0; mf < 4; ++mf)
#pragma unroll
            for (int nf = 0; nf < 2; ++nf) {
                int cc = c0 + nf * 16 + l15;
                int rr = mf * 16 + g * 4;
                bf16x4 pk;
#pragma unroll
                for (int r = 0; r < 4; ++r) {
                    float v = acc[mf][nf][r];
                    pk[r] = (bf16)(isk ? __expf(v) : v);
                }
                if (isk) *(bf16x4*)(&ekT[bs][cc][rr]) = pk;
                else     *(bf16x4*)(&vT[bs][cc][rr]) = pk;
            }
        __syncthreads();  // ekT/vT[bs] ready
#pragma unroll
        for (int k2 = 0; k2 < 2; ++k2) {
            bf16x8 bv = *(const bf16x8*)(&vT[bs][w * 16 + l15][k2 * 32 + g * 8]);
#pragma unroll
            for (int df = 0; df < 4; ++df) {
                bf16x8 ae = *(const bf16x8*)(&ekT[bs][df * 16 + l15][k2 * 32 + g * 8]);
                uacc[df] = mfma16(ae, bv, uacc[df]);
            }
        }
        {
#pragma unroll
            for (int i = 0; i < 16; ++i) sreg += (float)ekT[bs][l][w * 16 + i];
        }
    }
    int bh = b * 8 + h;
    float* Ubh = U + (size_t)bh * 4096;
#pragma unroll
    for (int df = 0; df < 4; ++df)
#pragma unroll
        for (int r = 0; r < 4; ++r)
            atomicAdd(Ubh + (df * 16 + g * 4 + r) * 64 + w * 16 + l15, uacc[df][r]);
    atomicAdd(S + bh * 64 + l, sreg);
}

// ---- attn = U/S ; M2 packed-fragment output ---- (r15-proven, unchanged)
__global__ void __launch_bounds__(256) k_attn_m2(const float* __restrict__ U,
                                                 const float* __restrict__ S,
                                                 const float* __restrict__ cw,
                                                 bf16* __restrict__ m2t) {
    __shared__ float at[16][64];
    int b = blockIdx.x & 7, dq = (blockIdx.x >> 3) & 3, h = blockIdx.x >> 5;
    int tid = threadIdx.x;
    const float* Ub = U + (size_t)(b * 8 + h) * 4096 + dq * 16 * 64;
    const float* Sb = S + (b * 8 + h) * 64 + dq * 16;
    for (int it = 0; it < 4; ++it) {
        int idx = it * 256 + tid;  // 0..1023
        at[idx >> 6][idx & 63] = Ub[idx] / Sb[idx >> 6];
    }
    __syncthreads();
    int o = tid;
    float cwr[64];
#pragma unroll
    for (int e = 0; e < 64; ++e) cwr[e] = cw[(size_t)o * 512 + h * 64 + e];
    bf16* mb = m2t + (size_t)b * 131072;
    int pp = o >> 4, l15o = o & 15;
#pragma unroll
    for (int j0 = 0; j0 < 16; j0 += 8) {
        bf16x8 pk;
#pragma unroll
        for (int j = 0; j < 8; ++j) {
            float a2 = 0.f;
#pragma unroll
            for (int e = 0; e < 64; ++e) a2 += at[j0 + j][e] * cwr[e];
            pk[j] = (bf16)a2;
        }
        int kk = dq * 16 + j0;                 // k within head, 0..56
        int ksg = h * 2 + (kk >> 5);           // global ks (0..15)
        int gg = (kk >> 3) & 3;
        *(bf16x8*)(mb + ((size_t)((pp * 16 + ksg) * 64 + gg * 16 + l15o)) * 8) = pk;
    }
}

// ---- fused: q GEMM + per-head softmax + (qsm @ M2T) + bias + rmsnorm + residual ----
// EXACT r15-proven form (89.2us round).
__global__ void __launch_bounds__(512, 4) k_qout(const bf16* __restrict__ t,
                                                 const bf16* __restrict__ wqb,
                                                 const bf16* __restrict__ m2t,
                                                 const float* __restrict__ gffn,
                                                 const float* __restrict__ cb,
                                                 float* __restrict__ out) {
    __shared__ __align__(16) char smem[66560 + 2048];  // qsm/tS/obuf (66560) + rowsum[8][64]
    bf16 (*qsm)[520] = (bf16(*)[520])smem;
    float* rowsum = (float*)(smem + 66560);
    bf16* tS = (bf16*)smem;
    int b = blockIdx.x & 7;
    int row0 = (blockIdx.x >> 3) << 6;
    int tid = threadIdx.x;
    int w = tid >> 6, l = tid & 63;
    int l15 = l & 15, g = l >> 4;
    int xorm = (l15 & 7) << 4;
    const f32x4 fz = {0.f, 0.f, 0.f, 0.f};

    // stage t[64][256] (32KB) swizzled
    {
        const char* gt = (const char*)(t + (size_t)(b * N_ + row0) * 256);
#pragma unroll
        for (int it = 0; it < 4; ++it) {
            int o = it * 8192 + tid * 16;
            int src = o ^ (((o >> 9) & 7) << 4);
            gload_lds16(gt + src, (char*)tS + o);
        }
    }
    __syncthreads();  // drains vmcnt -> tS ready

    // phase 1: q = tS @ WqT (wave w: 64 rows x 64 cols = head w; panels w*4+nf)
    f32x4 acc[4][4];
#pragma unroll
    for (int mf = 0; mf < 4; ++mf)
#pragma unroll
        for (int nf = 0; nf < 4; ++nf) acc[mf][nf] = fz;
#pragma unroll
    for (int ks = 0; ks < 8; ++ks) {
        bf16x8 a[4];
#pragma unroll
        for (int mf = 0; mf < 4; ++mf)
            a[mf] = *(const bf16x8*)((const char*)tS + (mf * 16 + l15) * 512 + ((ks * 64 + g * 16) ^ xorm));
#pragma unroll
        for (int nf = 0; nf < 4; ++nf) {
            bf16x8 bq = *(const bf16x8*)(wqb + ((size_t)(((w * 4 + nf) * 8 + ks) * 64 + l)) * 8);
#pragma unroll
            for (int mf = 0; mf < 4; ++mf)
                acc[mf][nf] = mfma16(a[mf], bq, acc[mf][nf]);
        }
    }
    __syncthreads();  // all tS reads done before qsm overwrite

    // phase 2: softmax over head w's 64 d (this wave's 4 nf panels), -> qsm bf16
#pragma unroll
    for (int mf = 0; mf < 4; ++mf)
#pragma unroll
        for (int r = 0; r < 4; ++r) {
            float mx = -1e30f;
#pragma unroll
            for (int nf = 0; nf < 4; ++nf) mx = fmaxf(mx, acc[mf][nf][r]);
            mx = fmaxf(mx, __shfl_xor(mx, 1));
            mx = fmaxf(mx, __shfl_xor(mx, 2));
            mx = fmaxf(mx, __shfl_xor(mx, 4));
            mx = fmaxf(mx, __shfl_xor(mx, 8));
            float p[4]; float sm = 0.f;
#pragma unroll
            for (int nf = 0; nf < 4; ++nf) { p[nf] = __expf(acc[mf][nf][r] - mx); sm += p[nf]; }
            sm += __shfl_xor(sm, 1);
            sm += __shfl_xor(sm, 2);
            sm += __shfl_xor(sm, 4);
            sm += __shfl_xor(sm, 8);
            float scl = 0.125f / sm;
            int row = mf * 16 + g * 4 + r;
#pragma unroll
            for (int nf = 0; nf < 4; ++nf)
                qsm[row][w * 64 + nf * 16 + l15] = (bf16)(p[nf] * scl);
        }
    __syncthreads();

    // phase 3: out2 = qsm @ M2T (wave w: 64 rows x cols [w*32,w*32+32); panels w*2+nf)
    f32x4 acc2[4][2];
#pragma unroll
    for (int mf = 0; mf < 4; ++mf)
#pragma unroll
        for (int nf = 0; nf < 2; ++nf) acc2[mf][nf] = fz;
    const bf16* mb = m2t + (size_t)b * 131072;
#pragma unroll
    for (int ks = 0; ks < 16; ++ks) {
        bf16x8 a[4];
#pragma unroll
        for (int mf = 0; mf < 4; ++mf)
            a[mf] = *(const bf16x8*)(&qsm[mf * 16 + l15][ks * 32 + g * 8]);
#pragma unroll
        for (int nf = 0; nf < 2; ++nf) {
            bf16x8 bm = *(const bf16x8*)(mb + ((size_t)(((w * 2 + nf) * 16 + ks) * 64 + l)) * 8);
#pragma unroll
            for (int mf = 0; mf < 4; ++mf)
                acc2[mf][nf] = mfma16(a[mf], bm, acc2[mf][nf]);
        }
    }

    // phase 4: +bias, rmsnorm partials over this wave's 32 cols
#pragma unroll
    for (int nf = 0; nf < 2; ++nf) {
        float bias = cb[w * 32 + nf * 16 + l15];
#pragma unroll
        for (int mf = 0; mf < 4; ++mf)
#pragma unroll
            for (int r = 0; r < 4; ++r) acc2[mf][nf][r] += bias;
    }
#pragma unroll
    for (int mf = 0; mf < 4; ++mf)
#pragma unroll
        for (int r = 0; r < 4; ++r) {
            float ssq = 0.f;
#pragma unroll
            for (int nf = 0; nf < 2; ++nf) ssq += acc2[mf][nf][r] * acc2[mf][nf][r];
            ssq += __shfl_xor(ssq, 1);
            ssq += __shfl_xor(ssq, 2);
            ssq += __shfl_xor(ssq, 4);
            ssq += __shfl_xor(ssq, 8);
            if (l15 == 0) rowsum[w * 64 + mf * 16 + g * 4 + r] = ssq;
        }
    __syncthreads();  // rowsum complete + all phase-3 qsm reads done
    float sclr[4][4];
#pragma unroll
    for (int mf = 0; mf < 4; ++mf)
#pragma unroll
        for (int r = 0; r < 4; ++r) {
            int row = mf * 16 + g * 4 + r;
            float tot = 0.f;
#pragma unroll
            for (int ww = 0; ww < 8; ++ww) tot += rowsum[ww * 64 + row];
            sclr[mf][r] = 16.0f / fmaxf(sqrtf(tot), 1e-12f);
        }

    // epilogue: obuf[col][row] = acc2*scl*gffn + residual (re-read t; L2-hot).
    float* obuf = (float*)smem;
    const bf16* gtb = t + (size_t)(b * N_ + row0) * 256;
#pragma unroll
    for (int nf = 0; nf < 2; ++nf) {
        int col = w * 32 + nf * 16 + l15;
        float gf = gffn[col];
#pragma unroll
        for (int mf = 0; mf < 4; ++mf)
#pragma unroll
            for (int r = 0; r < 4; ++r) {
                int row = mf * 16 + g * 4 + r;
                float res = (float)gtb[row * 256 + col];
                obuf[col * 65 + row] = acc2[mf][nf][r] * sclr[mf][r] * gf + res;
            }
    }
    __syncthreads();
    // coalesced read-back: 16 lanes cover one col's 64 floats (256B), nontemporal
#pragma unroll
    for (int cc = 0; cc < 8; ++cc) {
        int c = cc * 32 + (tid >> 4);
        int j = (tid & 15) * 4;
        f32x4 v;
#pragma unroll
        for (int r = 0; r < 4; ++r) v[r] = obuf[c * 65 + j + r];
        __builtin_nontemporal_store(v, (f32x4*)(out + ((size_t)(b * 256 + c)) * N_ + row0 + j));
    }
}

extern "C" void kernel_launch(void* const* d_in, const int* in_sizes, int n_in,
                              void* d_out, int out_size, void* d_ws, size_t ws_size,
                              hipStream_t stream) {
    const float* x     = (const float*)d_in[0];
    const float* Wq    = (const float*)d_in[1];
    const float* Wk    = (const float*)d_in[2];
    const float* Wv    = (const float*)d_in[3];
    const float* cw    = (const float*)d_in[4];
    const float* cb    = (const float*)d_in[5];
    const float* gffn  = (const float*)d_in[6];
    const float* gnorm = (const float*)d_in[7];
    char* ws = (char*)d_ws;
    bf16* t    = (bf16*)(ws + T_OFF);
    float* U   = (float*)(ws + U_OFF);
    float* S   = (float*)(ws + S_OFF);
    bf16* m2t  = (bf16*)(ws + M2T_OFF);
    bf16* wqb  = (bf16*)(ws + WQ_OFF);
    bf16* wkb  = (bf16*)(ws + WK_OFF);
    bf16* wvb  = (bf16*)(ws + WV_OFF);
    float* out = (float*)d_out;

    k_nc<<<736, 256, 0, stream>>>(x, gnorm, t, Wq, Wk, Wv, wqb, wkb, wvb, U);
    k_kv<<<512, 256, 0, stream>>>(t, wkb, wvb, U, S);
    k_attn_m2<<<256, 256, 0, stream>>>(U, S, cw, m2t);
    k_qout<<<512, 512, 0, stream>>>(t, wqb, m2t, gffn, cb, out);
}